// Round 11
// baseline (156.874 us; speedup 1.0000x reference)
//
#include <hip/hip_runtime.h>
#include <math.h>

#define B_  16
#define L_  4096
#define D_  64
#define R_  4
#define NB_ 64
#define BL_ 64

typedef _Float16 f16x8 __attribute__((ext_vector_type(8)));
typedef _Float16 f16x4 __attribute__((ext_vector_type(4)));
typedef _Float16 f16x2 __attribute__((ext_vector_type(2)));
typedef float    f32x4 __attribute__((ext_vector_type(4)));

// ---------------- ws layout ----------------
// [1MB,2MB)     h      int      [B][R][L]   (bit30 = ambiguous flag)
// [4MB,5MB)     lse    float    [B][R][L]   (original index)
// [5MB,+256)    rwmax float[64]; [+256,+512) rwsum
// [6MB,40MB)    attn   _Float16 [B][R][L][64]  (original index)
// [41MB,43MB)   metaA  int2     [B*R][L]   (.x=bucket_start_spos, .y=p)  per sorted pos
// [43MB,+256K)  packB  u8       [B][L][4]  bk byte per round, per original idx
// [45MB,+256K)  qscale float    [B][L]     ||q|| / (0.125*log2e)
// [53MB,61MB)   khf    _Float16 [B][L][64]   q/||q|| * log2e/8, f16   (log2 domain!)
// [61MB,69MB)   vhf    _Float16 [B][L][64]   v, f16
// rm layout: rm[b*8192 + d*128 + r*32 + n]

// K1: split-f16 MFMA hash + f16 tensor prep; rm normalized in-block (f32);
// ambiguous rows flagged via bit30 of h (resolved exactly inside k_sort).
__global__ __launch_bounds__(256, 4) void k_hash(const float* __restrict__ q,
                                                 const float* __restrict__ value,
                                                 const float* __restrict__ rm,
                                                 int* __restrict__ h_ws,
                                                 float* __restrict__ qscale_g,
                                                 _Float16* __restrict__ khf,
                                                 _Float16* __restrict__ vhf) {
    __shared__ __align__(16) char smem[36864];
    _Float16* Rhi = (_Float16*)smem;            // [128][72]
    _Float16* Rlo = (_Float16*)(smem + 18432);  // [128][72]
    float*    Sc  = (float*)smem;               // overlay [64][133]

    int blk = blockIdx.x;                 // b*64 + chunk
    int b = blk >> 6, chunk = blk & 63;
    int tid = threadIdx.x;
    int w = tid >> 6, lane = tid & 63, quad = lane >> 4, l15 = lane & 15;

    {   // vhf prep: 64 rows of v -> f16 (streaming, no LDS)
        int row = chunk * 64 + (tid >> 2), sub = tid & 3;
        const float4* vp = (const float4*)(value + ((size_t)(b * L_ + row)) * 64 + sub * 16);
        f16x8 h0, h1;
        #pragma unroll
        for (int c = 0; c < 2; c++) {
            float4 t0 = vp[2 * c], t1 = vp[2 * c + 1];
            f16x8& hd = c ? h1 : h0;
            hd[0]=(_Float16)t0.x; hd[1]=(_Float16)t0.y; hd[2]=(_Float16)t0.z; hd[3]=(_Float16)t0.w;
            hd[4]=(_Float16)t1.x; hd[5]=(_Float16)t1.y; hd[6]=(_Float16)t1.z; hd[7]=(_Float16)t1.w;
        }
        _Float16* dst = vhf + ((size_t)(b * L_ + row)) * 64 + sub * 16;
        *(f16x8*)dst = h0;
        *(f16x8*)(dst + 8) = h1;
    }

    {   // stage R: in-block f32 normalize of rm + hi/lo split (2 threads/row)
        int row = tid >> 1, dh2 = (tid & 1) * 32;   // row = r*32+n
        int rr = row >> 5, nn = row & 31;
        const float* rpb = rm + (size_t)b * 8192 + rr * 32 + nn;
        float ss = 0.f;
        #pragma unroll
        for (int g = 0; g < 32; g++) { float v = rpb[(dh2 + g) * 128]; ss += v * v; }
        ss += __shfl_xor(ss, 1);                    // pair (dh=0, dh=1) same wave
        float rn = 1.0f / sqrtf(ss);
        #pragma unroll
        for (int gg = 0; gg < 4; gg++) {
            f16x8 hv, lv;
            #pragma unroll
            for (int e = 0; e < 8; e++) {
                float f = rpb[(dh2 + gg * 8 + e) * 128] * rn;   // L1-hot reload
                _Float16 h = (_Float16)f;
                hv[e] = h; lv[e] = (_Float16)(f - (float)h);
            }
            *(f16x8*)&Rhi[row * 72 + dh2 + gg * 8] = hv;
            *(f16x8*)&Rlo[row * 72 + dh2 + gg * 8] = lv;
        }
    }

    int qrow = chunk * 64 + w * 16 + l15;
    const float* qp = q + ((size_t)(b * L_ + qrow)) * 64;
    float qv[16];
    #pragma unroll
    for (int kt = 0; kt < 2; kt++) {
        float4 t0 = *(const float4*)(qp + kt * 32 + quad * 8);
        float4 t1 = *(const float4*)(qp + kt * 32 + quad * 8 + 4);
        qv[8*kt+0]=t0.x; qv[8*kt+1]=t0.y; qv[8*kt+2]=t0.z; qv[8*kt+3]=t0.w;
        qv[8*kt+4]=t1.x; qv[8*kt+5]=t1.y; qv[8*kt+6]=t1.z; qv[8*kt+7]=t1.w;
    }
    f16x8 Ahi[2], Alo[2];
    #pragma unroll
    for (int kt = 0; kt < 2; kt++) {
        #pragma unroll
        for (int j = 0; j < 8; j++) {
            _Float16 hi = (_Float16)qv[8*kt+j];
            Ahi[kt][j] = hi;
            Alo[kt][j] = (_Float16)(qv[8*kt+j] - (float)hi);
        }
    }
    {   // khf (normalized, scaled f16, log2-domain) + qscale
        float ss = 0.f;
        #pragma unroll
        for (int j = 0; j < 16; j++) ss += qv[j] * qv[j];
        ss += __shfl_xor(ss, 16);
        ss += __shfl_xor(ss, 32);
        float nr = sqrtf(ss); if (nr < 1e-12f) nr = 1e-12f;
        float kscale = 0.18033688f / nr;   // c = 0.125 * log2(e)
        if (quad == 0) qscale_g[(size_t)b * L_ + qrow] = nr * 5.5451774445f;  // nr / c
        _Float16* kd = khf + ((size_t)(b * L_ + qrow)) * 64;
        #pragma unroll
        for (int kt = 0; kt < 2; kt++) {
            f16x8 hv;
            #pragma unroll
            for (int j = 0; j < 8; j++) hv[j] = (_Float16)(qv[8*kt+j] * kscale);
            *(f16x8*)(kd + kt * 32 + quad * 8) = hv;
        }
    }
    __syncthreads();

    f32x4 acc[8];
    #pragma unroll
    for (int jt = 0; jt < 8; jt++) acc[jt] = (f32x4){0.f, 0.f, 0.f, 0.f};
    #pragma unroll
    for (int jt = 0; jt < 8; jt++) {
        #pragma unroll
        for (int kt = 0; kt < 2; kt++) {
            f16x8 bh = *(const f16x8*)&Rhi[(jt * 16 + l15) * 72 + kt * 32 + quad * 8];
            f16x8 bl = *(const f16x8*)&Rlo[(jt * 16 + l15) * 72 + kt * 32 + quad * 8];
            acc[jt] = __builtin_amdgcn_mfma_f32_16x16x32_f16(Ahi[kt], bh, acc[jt], 0, 0, 0);
            acc[jt] = __builtin_amdgcn_mfma_f32_16x16x32_f16(Ahi[kt], bl, acc[jt], 0, 0, 0);
            acc[jt] = __builtin_amdgcn_mfma_f32_16x16x32_f16(Alo[kt], bh, acc[jt], 0, 0, 0);
        }
    }
    __syncthreads();

    #pragma unroll
    for (int jt = 0; jt < 8; jt++) {
        #pragma unroll
        for (int reg = 0; reg < 4; reg++)
            Sc[(w * 16 + quad * 4 + reg) * 133 + jt * 16 + l15] = acc[jt][reg];
    }
    __syncthreads();

    {
        // top-2 of |v| with sign-tagged argmax. Ambiguous (v1-v2 < 4e-5):
        // flag bit30; k_sort resolves exactly with reference tie order.
        int row = tid & 63, r = tid >> 6;
        const float* sp = &Sc[row * 133 + r * 32];
        float v1 = -1e30f, v2 = -1e30f; int i1 = 0;
        #pragma unroll
        for (int n = 0; n < 32; n++) {
            float v = sp[n];
            float a = fabsf(v);
            int cand = n | ((__float_as_uint(v) >> 26) & 32);
            if (a > v1) i1 = cand;
            v2 = __builtin_amdgcn_fmed3f(a, v1, v2);
            v1 = fmaxf(a, v1);
        }
        int l = chunk * 64 + row;
        if (v1 - v2 < 4e-5f) i1 |= (1 << 30);
        h_ws[((size_t)(b * 4 + r)) * L_ + l] = i1;
    }
}

// K2: fused exact-fix + stable counting sort per (b,r).
// Emits metaA (spos -> {bucket_start, p}, coalesced) and this round's bk byte
// of packB (per original idx). All scatters stay in LDS.
__global__ __launch_bounds__(256) void k_sort(const int* __restrict__ h_ws,
                                              const float* __restrict__ q,
                                              const float* __restrict__ rm,
                                              int2* __restrict__ metaA,
                                              unsigned char* __restrict__ packB) {
    __shared__ __align__(16) unsigned short cnt[64 * 257];   // [bucket][thread]
    __shared__ __align__(16) unsigned short oi_s[256 * 17];  // padded [t][k]: orig->pos
    __shared__ __align__(16) unsigned short p_s[4096];       // fixmap, then spos->p
    __shared__ __align__(16) unsigned short sb_s[4096];      // fixlist, then spos->bstart
    __shared__ int part[256];                                // [seg][bucket] bases
    __shared__ int bstart_s[64];
    __shared__ int flcnt;

    int br = blockIdx.x;
    int b = br >> 2, r = br & 3;
    int t = threadIdx.x;
    const int* hp = h_ws + (size_t)br * L_;

    if (t == 0) flcnt = 0;

    // load keys (coalesced int4), strip + remember flags
    int key[16]; unsigned fmask = 0;
    const int4* hp4 = (const int4*)(hp + t * 16);
    #pragma unroll
    for (int g = 0; g < 4; g++) {
        int4 v = hp4[g];
        int raw[4] = { v.x, v.y, v.z, v.w };
        #pragma unroll
        for (int j = 0; j < 4; j++) {
            int k = g * 4 + j;
            key[k] = raw[j] & 63;
            if (raw[j] & (1 << 30)) fmask |= 1u << k;
        }
    }
    __syncthreads();   // flcnt=0 visible

    if (fmask) {
        #pragma unroll
        for (int k = 0; k < 16; k++)
            if (fmask & (1u << k)) {
                int slot = atomicAdd(&flcnt, 1);
                sb_s[slot] = (unsigned short)(t * 16 + k);   // row l (<=4096 entries)
            }
    }
    __syncthreads();

    {   // wave-cooperative exact fp64 resolve (reference tie order)
        int wid = t >> 6, lane = t & 63;
        int fc = flcnt;
        for (int e = wid; e < fc; e += 4) {
            int l = sb_s[e];
            int n = lane & 31;
            const float* rpb = rm + (size_t)b * 8192 + r * 32 + n;
            const float* qr = q + ((size_t)(b * L_ + l)) * 64;
            double s2 = 0.0, dot = 0.0;
            for (int d = 0; d < 64; d++) {
                double m = (double)rpb[d * 128];
                s2 += m * m;
                dot += (double)qr[d] * m;
            }
            double acc = dot / sqrt(s2);
            double v = (lane < 32) ? acc : -acc;
            int idx = lane;
            #pragma unroll
            for (int off = 1; off < 64; off <<= 1) {
                double ov = __shfl_xor(v, off);
                int   oidx = __shfl_xor(idx, off);
                if (ov > v || (ov == v && oidx < idx)) { v = ov; idx = oidx; }
            }
            if (lane == 0) p_s[l] = (unsigned short)idx;
        }
    }
    __syncthreads();
    if (fmask) {
        #pragma unroll
        for (int k = 0; k < 16; k++)
            if (fmask & (1u << k)) key[k] = p_s[t * 16 + k];
    }

    // zero histogram (16448 u16 = 8224 u32)
    unsigned int* cz = (unsigned int*)cnt;
    #pragma unroll
    for (int i = 0; i < 33; i++) {
        int idx = i * 256 + t;
        if (idx < 8224) cz[idx] = 0;
    }
    __syncthreads();

    // per-thread histogram
    #pragma unroll
    for (int k = 0; k < 16; k++) {
        unsigned short* c = &cnt[key[k] * 257 + t];
        *c = (unsigned short)(*c + 1);
    }
    __syncthreads();

    // within-segment exclusive prefix
    int u = t & 63, s = t >> 6;
    {
        int run = 0;
        int base_idx = u * 257 + s * 64;
        #pragma unroll 16
        for (int i = 0; i < 64; i++) {
            int c = cnt[base_idx + i];
            cnt[base_idx + i] = (unsigned short)run;
            run += c;
        }
        part[s * 64 + u] = run;
    }
    __syncthreads();

    if (t < 64) {
        int p0 = part[t], p1 = part[64 + t], p2 = part[128 + t], p3 = part[192 + t];
        int tot = p0 + p1 + p2 + p3;
        int v = tot;
        #pragma unroll
        for (int off = 1; off < 64; off <<= 1) {
            int o = __shfl_up(v, off);
            if (t >= off) v += o;
        }
        int base = v - tot;              // first spos of bucket t
        bstart_s[t] = base;
        part[t]       = base;
        part[64 + t]  = base + p0;
        part[128 + t] = base + p0 + p1;
        part[192 + t] = base + p0 + p1 + p2;
    }
    __syncthreads();

    // scatter: pos = bucket/segment base + within-segment offset (stable)
    int sbase = s * 64;
    #pragma unroll
    for (int k = 0; k < 16; k++) {
        int uk = key[k];
        unsigned short* c = &cnt[uk * 257 + t];
        int pos = part[sbase + uk] + *c;
        *c = (unsigned short)(*c + 1);
        int idx = t * 16 + k;
        oi_s[(idx >> 4) * 17 + (idx & 15)] = (unsigned short)pos;
        p_s[pos]  = (unsigned short)idx;
        sb_s[pos] = (unsigned short)bstart_s[uk];
    }
    __syncthreads();

    // coalesced outputs: metaA (int2 per spos) + this round's bk byte per orig idx
    int2* mp = metaA + (size_t)br * L_;
    unsigned char* pb = packB + ((size_t)b * L_) * 4 + r;
    #pragma unroll
    for (int k = 0; k < 16; k++) {
        int e = k * 256 + t;
        mp[e] = make_int2((int)sb_s[e], (int)p_s[e]);
        int pos = (int)oi_s[(e >> 4) * 17 + (e & 15)];
        pb[(size_t)e * 4] = (unsigned char)(pos >> 6);
    }
}

// K3: MFMA fused attention (256 threads, strides 72/136). PV computed as
// O^T = V^T * P^T (operand-swapped MFMA) so each lane's 4 accumulator regs
// hold 4 CONSECUTIVE d-values of one q-row: epilogue = one base address +
// 4 x 8B f16x4 stores (vs 16 x 2B scattered). Ph pre-normalized (inv folded).
__global__ __launch_bounds__(256, 4) void k_attn(const float* __restrict__ qscale_g,
                                                 const _Float16* __restrict__ khf,
                                                 const _Float16* __restrict__ vhf,
                                                 const int2* __restrict__ metaA,
                                                 const unsigned int* __restrict__ packA,
                                                 float* __restrict__ lse_ws,
                                                 _Float16* __restrict__ attn_ws) {
    __shared__ _Float16 Ksh[128 * 72];    // 18432 B; overlaid by Ph[64][136]
    __shared__ _Float16 Vt[64 * 136];     // 17408 B
    __shared__ int4 kmeta[128];

    int xcd = blockIdx.x & 7, slot = blockIdx.x >> 3;
    int b = xcd * 2 + (slot >> 8);
    int rem = slot & 255, n = rem >> 2, r = rem & 3;
    int tid = threadIdx.x;
    int w = tid >> 6, lane = tid & 63, quad = lane >> 4, l15 = lane & 15;
    int hibase = (b * 4 + r) * L_;
    const int2* mpA = metaA + hibase;
    int nprev = (n + 63) & 63;

    {   // stage K + publish kmeta
        int j = tid >> 1, dh = (tid & 1) * 32;
        int spos = (j < 64) ? (nprev * 64 + j) : (n * 64 + (j - 64));
        int2 ma = mpA[spos];
        const _Float16* src = khf + ((size_t)(b * L_ + ma.y)) * 64 + dh;
        f16x8 t0 = *(const f16x8*)(src);
        f16x8 t1 = *(const f16x8*)(src + 8);
        f16x8 t2 = *(const f16x8*)(src + 16);
        f16x8 t3 = *(const f16x8*)(src + 24);
        if (dh == 0) {
            unsigned int pk = packA[b * L_ + ma.y];
            unsigned int pm1 = ((pk | 0x40404040u) - 0x01010101u) & 0x3f3f3f3fu;
            kmeta[j] = make_int4(ma.x, ma.y, (int)pk, (int)pm1);
        }
        *(f16x8*)&Ksh[j * 72 + dh + 0]  = t0;
        *(f16x8*)&Ksh[j * 72 + dh + 8]  = t1;
        *(f16x8*)&Ksh[j * 72 + dh + 16] = t2;
        *(f16x8*)&Ksh[j * 72 + dh + 24] = t3;
    }
    __syncthreads();   // b1: Ksh + kmeta ready

    {   // stage V^T: thread = (row-pair m, d-quarter sub); rows from kmeta
        int m = tid >> 2, sub = tid & 3;
        int y0 = kmeta[2 * m].y, y1 = kmeta[2 * m + 1].y;
        const _Float16* v0 = vhf + ((size_t)(b * L_ + y0)) * 64 + sub * 16;
        const _Float16* v1 = vhf + ((size_t)(b * L_ + y1)) * 64 + sub * 16;
        f16x8 a00 = *(const f16x8*)v0, a01 = *(const f16x8*)(v0 + 8);
        f16x8 a10 = *(const f16x8*)v1, a11 = *(const f16x8*)(v1 + 8);
        #pragma unroll
        for (int d = 0; d < 8; d++) {
            f16x2 hv = { a00[d], a10[d] };
            *(f16x2*)&Vt[(sub * 16 + d) * 136 + 2 * m] = hv;
            f16x2 hw = { a01[d], a11[d] };
            *(f16x2*)&Vt[(sub * 16 + 8 + d) * 136 + 2 * m] = hw;
        }
    }

    // A-frags from LDS: q rows ARE Ksh rows 64..127 (khf, same scaling)
    f16x8 afr[2];
    afr[0] = *(const f16x8*)&Ksh[(64 + w * 16 + l15) * 72 + quad * 8];
    afr[1] = *(const f16x8*)&Ksh[(64 + w * 16 + l15) * 72 + 32 + quad * 8];

    // hoisted meta/scale loads — latency hides under the QK MFMA cluster
    int4 qm4[4]; int km4z[8]; float qs4[4];
    #pragma unroll
    for (int reg = 0; reg < 4; reg++) {
        qm4[reg] = kmeta[64 + w * 16 + quad * 4 + reg];
        qs4[reg] = qscale_g[(size_t)b * L_ + qm4[reg].y];
    }
    #pragma unroll
    for (int jt = 0; jt < 8; jt++) km4z[jt] = kmeta[jt * 16 + l15].z;

    // QK^T
    f32x4 acc[8];
    #pragma unroll
    for (int jt = 0; jt < 8; jt++) acc[jt] = (f32x4){0.f, 0.f, 0.f, 0.f};
    __builtin_amdgcn_s_setprio(1);
    #pragma unroll
    for (int jt = 0; jt < 8; jt++) {
        #pragma unroll
        for (int kt = 0; kt < 2; kt++) {
            f16x8 bfr = *(const f16x8*)&Ksh[(jt * 16 + l15) * 72 + kt * 32 + quad * 8];
            acc[jt] = __builtin_amdgcn_mfma_f32_16x16x32_f16(afr[kt], bfr, acc[jt], 0, 0, 0);
        }
    }
    __builtin_amdgcn_s_setprio(0);
    __syncthreads();   // b2: all QK reads of Ksh done -> overlay Ph

    _Float16* Ph = Ksh;
    float lse_r[4];
    #pragma unroll
    for (int reg = 0; reg < 4; reg++) {
        // valid k-columns form the contiguous range [lo, si); self at si.
        int lo = qm4[reg].x - (n - 1) * 64;          // bucket start in column space
        int width = w * 16 + quad * 4 + reg + 64 - lo;   // si - lo
        int jl = l15 - lo;
        float qs = qs4[reg];
        float s[8];
        #pragma unroll
        for (int jt = 0; jt < 8; jt++) {
            float v = acc[jt][reg] * qs;
            int ju = jt * 16 + jl;                   // j - lo
            v = ((unsigned)ju < (unsigned)width) ? v : -1.4426951e9f;
            if (ju == width) v = -144269.50f;        // self: -1e5 * log2e
            s[jt] = v;
        }
        float m = s[0];
        #pragma unroll
        for (int jt = 1; jt < 8; jt++) m = fmaxf(m, s[jt]);
        #pragma unroll
        for (int off = 1; off < 16; off <<= 1) m = fmaxf(m, __shfl_xor(m, off));
        float te[8], sum = 0.f;
        #pragma unroll
        for (int jt = 0; jt < 8; jt++) { te[jt] = __builtin_amdgcn_exp2f(s[jt] - m); sum += te[jt]; }
        #pragma unroll
        for (int off = 1; off < 16; off <<= 1) sum += __shfl_xor(sum, off);
        float inv = __builtin_amdgcn_rcpf(sum);
        lse_r[reg] = m * 0.6931472f + __logf(sum);
        int i = w * 16 + quad * 4 + reg;
        #pragma unroll
        for (int jt = 0; jt < 8; jt++) {
            int z1 = km4z[jt] ^ qm4[reg].z;
            int z2 = km4z[jt] ^ qm4[reg].w;
            int nz = __popc((z1 + 0x7f7f7f7f) & 0x80808080)
                   + __popc((z2 + 0x7f7f7f7f) & 0x80808080);
            float p = te[jt] * inv * __builtin_amdgcn_rcpf((float)(8 - nz));
            Ph[i * 136 + jt * 16 + l15] = (_Float16)p;
        }
    }
    if (l15 == 0) {
        #pragma unroll
        for (int reg = 0; reg < 4; reg++)
            lse_ws[hibase + qm4[reg].y] = lse_r[reg];
    }
    __syncthreads();   // b3: Ph ready

    // PV as O^T = V^T * P^T (swapped operands): lane -> O[q=w*16+l15][d contig]
    f32x4 oacc[4];
    #pragma unroll
    for (int nt = 0; nt < 4; nt++) oacc[nt] = (f32x4){0.f, 0.f, 0.f, 0.f};
    __builtin_amdgcn_s_setprio(1);
    #pragma unroll
    for (int kt = 0; kt < 4; kt++) {
        f16x8 pa = *(const f16x8*)&Ph[(w * 16 + l15) * 136 + kt * 32 + quad * 8];
        #pragma unroll
        for (int nt = 0; nt < 4; nt++) {
            f16x8 vb = *(const f16x8*)&Vt[(nt * 16 + l15) * 136 + kt * 32 + quad * 8];
            oacc[nt] = __builtin_amdgcn_mfma_f32_16x16x32_f16(vb, pa, oacc[nt], 0, 0, 0);
        }
    }
    __builtin_amdgcn_s_setprio(0);

    // direct store epilogue: one row base per thread, 4 x 8B f16x4 stores.
    // O[q = w*16+l15][d = nt*16 + quad*4 + reg]
    {
        int qy = kmeta[64 + w * 16 + l15].y;
        _Float16* dst = attn_ws + ((size_t)hibase + qy) * 64 + quad * 4;
        #pragma unroll
        for (int nt = 0; nt < 4; nt++) {
            f16x4 v;
            v[0] = (_Float16)oacc[nt][0];
            v[1] = (_Float16)oacc[nt][1];
            v[2] = (_Float16)oacc[nt][2];
            v[3] = (_Float16)oacc[nt][3];
            *(f16x4*)(dst + nt * 16) = v;
        }
    }
}

// K4a: per (b,r) softmax-over-L stats of lse
__global__ __launch_bounds__(256) void k_rw(const float* __restrict__ lse_ws,
                                            float* __restrict__ rwmax,
                                            float* __restrict__ rwsum) {
    __shared__ float  red[256];
    __shared__ double redd[256];
    int br = blockIdx.x;
    const float* lp = lse_ws + (size_t)br * L_;
    int t = threadIdx.x;
    float m = -1e30f;
    for (int k = t; k < L_; k += 256) m = fmaxf(m, lp[k]);
    red[t] = m; __syncthreads();
    for (int s2 = 128; s2 > 0; s2 >>= 1) {
        if (t < s2) red[t] = fmaxf(red[t], red[t + s2]);
        __syncthreads();
    }
    float mm = red[0];
    double s = 0.0;
    for (int k = t; k < L_; k += 256) s += (double)expf(lp[k] - mm);
    redd[t] = s; __syncthreads();
    for (int s2 = 128; s2 > 0; s2 >>= 1) {
        if (t < s2) redd[t] += redd[t + s2];
        __syncthreads();
    }
    if (t == 0) { rwmax[br] = mm; rwsum[br] = (float)redd[0]; }
}

// K4b: vectorized combine — thread = (b,l, d-octet)
__global__ __launch_bounds__(256) void k_out(const _Float16* __restrict__ attn_ws,
                                             const float* __restrict__ lse_ws,
                                             const float* __restrict__ rwmax,
                                             const float* __restrict__ rwsum,
                                             float* __restrict__ out) {
    int gid = blockIdx.x * 256 + threadIdx.x;   // B*L*8
    int g = gid & 7;
    size_t row = (size_t)(gid >> 3);            // b*L + l
    int b = (int)(row >> 12), l = (int)(row & 4095);
    float o[8];
    #pragma unroll
    for (int k = 0; k < 8; k++) o[k] = 0.f;
    #pragma unroll
    for (int r = 0; r < 4; r++) {
        int br = b * 4 + r;
        float wgt = __expf(lse_ws[(size_t)br * L_ + l] - rwmax[br])
                  * __builtin_amdgcn_rcpf(rwsum[br]);
        f16x8 av = *(const f16x8*)&attn_ws[(((size_t)br * L_ + l) << 6) + g * 8];
        #pragma unroll
        for (int k = 0; k < 8; k++) o[k] += (float)av[k] * wgt;
    }
    float4* op = (float4*)(out + row * 64 + g * 8);
    op[0] = make_float4(o[0], o[1], o[2], o[3]);
    op[1] = make_float4(o[4], o[5], o[6], o[7]);
}

extern "C" void kernel_launch(void* const* d_in, const int* in_sizes, int n_in,
                              void* d_out, int out_size, void* d_ws, size_t ws_size,
                              hipStream_t stream) {
    const float* query = (const float*)d_in[0];
    const float* value = (const float*)d_in[1];
    const float* rm    = (const float*)d_in[2];
    char* ws = (char*)d_ws;
    int*       h_ws   = (int*)(ws + ((size_t)1 << 20));
    float*     lse_ws = (float*)(ws + ((size_t)4 << 20));
    float*     rwmax  = (float*)(ws + ((size_t)5 << 20));
    float*     rwsum  = (float*)(ws + ((size_t)5 << 20) + 256);
    _Float16*  attn_ws= (_Float16*)(ws + ((size_t)6 << 20));
    int2*      metaA  = (int2*)(ws + ((size_t)41 << 20));
    unsigned char* packB = (unsigned char*)(ws + ((size_t)43 << 20));
    float*     qscale = (float*)(ws + ((size_t)45 << 20));
    _Float16*  khf    = (_Float16*)(ws + ((size_t)53 << 20));
    _Float16*  vhf    = (_Float16*)(ws + ((size_t)61 << 20));
    float*     out    = (float*)d_out;

    hipLaunchKernelGGL(k_hash,   dim3(1024), dim3(256), 0, stream, query, value, rm,
                       h_ws, qscale, khf, vhf);
    hipLaunchKernelGGL(k_sort,   dim3(64),   dim3(256), 0, stream, h_ws, query, rm,
                       metaA, packB);
    hipLaunchKernelGGL(k_attn,   dim3(4096), dim3(256), 0, stream,
                       qscale, khf, vhf, metaA, (const unsigned int*)packB, lse_ws, attn_ws);
    hipLaunchKernelGGL(k_rw,     dim3(64),   dim3(256), 0, stream, lse_ws, rwmax, rwsum);
    hipLaunchKernelGGL(k_out,    dim3(2048), dim3(256), 0, stream,
                       attn_ws, lse_ws, rwmax, rwsum, out);
}

// Round 12
// 151.317 us; speedup vs baseline: 1.0367x; 1.0367x over previous
//
#include <hip/hip_runtime.h>
#include <math.h>

#define B_  16
#define L_  4096
#define D_  64
#define R_  4
#define NB_ 64
#define BL_ 64

typedef _Float16 f16x8 __attribute__((ext_vector_type(8)));
typedef _Float16 f16x4 __attribute__((ext_vector_type(4)));
typedef _Float16 f16x2 __attribute__((ext_vector_type(2)));
typedef float    f32x4 __attribute__((ext_vector_type(4)));

// ---------------- ws layout ----------------
// [1MB,2MB)     h      int      [B][R][L]   (bit30 = ambiguous flag)
// [4MB,5MB)     lse    float    [B][R][L]   (original index)
// [5MB,+256)    rwmax float[64]; [+256,+512) rwsum
// [6MB,40MB)    attn   _Float16 [B][R][L][64]  (original index)
// [41MB,43MB)   metaA  int2     [B*R][L]   (.x=bucket_start_spos, .y=p)  per sorted pos
// [43MB,+256K)  packB  u8       [B][L][4]  bk byte per round, per original idx
// [45MB,+256K)  qscale float    [B][L]     ||q|| / (0.125*log2e)
// [53MB,61MB)   khf    _Float16 [B][L][64]   q/||q|| * log2e/8, f16   (log2 domain!)
// [61MB,69MB)   vhf    _Float16 [B][L][64]   v, f16
// rm layout: rm[b*8192 + d*128 + r*32 + n]

// K1: split-f16 MFMA hash + f16 tensor prep; rm normalized in-block (f32);
// ambiguous rows flagged via bit30 of h (resolved exactly inside k_sort).
__global__ __launch_bounds__(256, 4) void k_hash(const float* __restrict__ q,
                                                 const float* __restrict__ value,
                                                 const float* __restrict__ rm,
                                                 int* __restrict__ h_ws,
                                                 float* __restrict__ qscale_g,
                                                 _Float16* __restrict__ khf,
                                                 _Float16* __restrict__ vhf) {
    __shared__ __align__(16) char smem[36864];
    _Float16* Rhi = (_Float16*)smem;            // [128][72]
    _Float16* Rlo = (_Float16*)(smem + 18432);  // [128][72]
    float*    Sc  = (float*)smem;               // overlay [64][133]

    int blk = blockIdx.x;                 // b*64 + chunk
    int b = blk >> 6, chunk = blk & 63;
    int tid = threadIdx.x;
    int w = tid >> 6, lane = tid & 63, quad = lane >> 4, l15 = lane & 15;

    {   // vhf prep: 64 rows of v -> f16 (streaming, no LDS)
        int row = chunk * 64 + (tid >> 2), sub = tid & 3;
        const float4* vp = (const float4*)(value + ((size_t)(b * L_ + row)) * 64 + sub * 16);
        f16x8 h0, h1;
        #pragma unroll
        for (int c = 0; c < 2; c++) {
            float4 t0 = vp[2 * c], t1 = vp[2 * c + 1];
            f16x8& hd = c ? h1 : h0;
            hd[0]=(_Float16)t0.x; hd[1]=(_Float16)t0.y; hd[2]=(_Float16)t0.z; hd[3]=(_Float16)t0.w;
            hd[4]=(_Float16)t1.x; hd[5]=(_Float16)t1.y; hd[6]=(_Float16)t1.z; hd[7]=(_Float16)t1.w;
        }
        _Float16* dst = vhf + ((size_t)(b * L_ + row)) * 64 + sub * 16;
        *(f16x8*)dst = h0;
        *(f16x8*)(dst + 8) = h1;
    }

    {   // stage R: in-block f32 normalize of rm + hi/lo split (2 threads/row)
        int row = tid >> 1, dh2 = (tid & 1) * 32;   // row = r*32+n
        int rr = row >> 5, nn = row & 31;
        const float* rpb = rm + (size_t)b * 8192 + rr * 32 + nn;
        float ss = 0.f;
        #pragma unroll
        for (int g = 0; g < 32; g++) { float v = rpb[(dh2 + g) * 128]; ss += v * v; }
        ss += __shfl_xor(ss, 1);                    // pair (dh=0, dh=1) same wave
        float rn = 1.0f / sqrtf(ss);
        #pragma unroll
        for (int gg = 0; gg < 4; gg++) {
            f16x8 hv, lv;
            #pragma unroll
            for (int e = 0; e < 8; e++) {
                float f = rpb[(dh2 + gg * 8 + e) * 128] * rn;   // L1-hot reload
                _Float16 h = (_Float16)f;
                hv[e] = h; lv[e] = (_Float16)(f - (float)h);
            }
            *(f16x8*)&Rhi[row * 72 + dh2 + gg * 8] = hv;
            *(f16x8*)&Rlo[row * 72 + dh2 + gg * 8] = lv;
        }
    }

    int qrow = chunk * 64 + w * 16 + l15;
    const float* qp = q + ((size_t)(b * L_ + qrow)) * 64;
    float qv[16];
    #pragma unroll
    for (int kt = 0; kt < 2; kt++) {
        float4 t0 = *(const float4*)(qp + kt * 32 + quad * 8);
        float4 t1 = *(const float4*)(qp + kt * 32 + quad * 8 + 4);
        qv[8*kt+0]=t0.x; qv[8*kt+1]=t0.y; qv[8*kt+2]=t0.z; qv[8*kt+3]=t0.w;
        qv[8*kt+4]=t1.x; qv[8*kt+5]=t1.y; qv[8*kt+6]=t1.z; qv[8*kt+7]=t1.w;
    }
    f16x8 Ahi[2], Alo[2];
    #pragma unroll
    for (int kt = 0; kt < 2; kt++) {
        #pragma unroll
        for (int j = 0; j < 8; j++) {
            _Float16 hi = (_Float16)qv[8*kt+j];
            Ahi[kt][j] = hi;
            Alo[kt][j] = (_Float16)(qv[8*kt+j] - (float)hi);
        }
    }
    {   // khf (normalized, scaled f16, log2-domain) + qscale
        float ss = 0.f;
        #pragma unroll
        for (int j = 0; j < 16; j++) ss += qv[j] * qv[j];
        ss += __shfl_xor(ss, 16);
        ss += __shfl_xor(ss, 32);
        float nr = sqrtf(ss); if (nr < 1e-12f) nr = 1e-12f;
        float kscale = 0.18033688f / nr;   // c = 0.125 * log2(e)
        if (quad == 0) qscale_g[(size_t)b * L_ + qrow] = nr * 5.5451774445f;  // nr / c
        _Float16* kd = khf + ((size_t)(b * L_ + qrow)) * 64;
        #pragma unroll
        for (int kt = 0; kt < 2; kt++) {
            f16x8 hv;
            #pragma unroll
            for (int j = 0; j < 8; j++) hv[j] = (_Float16)(qv[8*kt+j] * kscale);
            *(f16x8*)(kd + kt * 32 + quad * 8) = hv;
        }
    }
    __syncthreads();

    f32x4 acc[8];
    #pragma unroll
    for (int jt = 0; jt < 8; jt++) acc[jt] = (f32x4){0.f, 0.f, 0.f, 0.f};
    #pragma unroll
    for (int jt = 0; jt < 8; jt++) {
        #pragma unroll
        for (int kt = 0; kt < 2; kt++) {
            f16x8 bh = *(const f16x8*)&Rhi[(jt * 16 + l15) * 72 + kt * 32 + quad * 8];
            f16x8 bl = *(const f16x8*)&Rlo[(jt * 16 + l15) * 72 + kt * 32 + quad * 8];
            acc[jt] = __builtin_amdgcn_mfma_f32_16x16x32_f16(Ahi[kt], bh, acc[jt], 0, 0, 0);
            acc[jt] = __builtin_amdgcn_mfma_f32_16x16x32_f16(Ahi[kt], bl, acc[jt], 0, 0, 0);
            acc[jt] = __builtin_amdgcn_mfma_f32_16x16x32_f16(Alo[kt], bh, acc[jt], 0, 0, 0);
        }
    }
    __syncthreads();

    #pragma unroll
    for (int jt = 0; jt < 8; jt++) {
        #pragma unroll
        for (int reg = 0; reg < 4; reg++)
            Sc[(w * 16 + quad * 4 + reg) * 133 + jt * 16 + l15] = acc[jt][reg];
    }
    __syncthreads();

    {
        // top-2 of |v| with sign-tagged argmax. Ambiguous (v1-v2 < 4e-5):
        // flag bit30; k_sort resolves exactly with reference tie order.
        int row = tid & 63, r = tid >> 6;
        const float* sp = &Sc[row * 133 + r * 32];
        float v1 = -1e30f, v2 = -1e30f; int i1 = 0;
        #pragma unroll
        for (int n = 0; n < 32; n++) {
            float v = sp[n];
            float a = fabsf(v);
            int cand = n | ((__float_as_uint(v) >> 26) & 32);
            if (a > v1) i1 = cand;
            v2 = __builtin_amdgcn_fmed3f(a, v1, v2);
            v1 = fmaxf(a, v1);
        }
        int l = chunk * 64 + row;
        if (v1 - v2 < 4e-5f) i1 |= (1 << 30);
        h_ws[((size_t)(b * 4 + r)) * L_ + l] = i1;
    }
}

// K2: fused exact-fix + stable counting sort per (b,r).
// Emits metaA (spos -> {bucket_start, p}, coalesced) and this round's bk byte
// of packB (per original idx). All scatters stay in LDS.
__global__ __launch_bounds__(256) void k_sort(const int* __restrict__ h_ws,
                                              const float* __restrict__ q,
                                              const float* __restrict__ rm,
                                              int2* __restrict__ metaA,
                                              unsigned char* __restrict__ packB) {
    __shared__ __align__(16) unsigned short cnt[64 * 257];   // [bucket][thread]
    __shared__ __align__(16) unsigned short oi_s[256 * 17];  // padded [t][k]: orig->pos
    __shared__ __align__(16) unsigned short p_s[4096];       // fixmap, then spos->p
    __shared__ __align__(16) unsigned short sb_s[4096];      // fixlist, then spos->bstart
    __shared__ int part[256];                                // [seg][bucket] bases
    __shared__ int bstart_s[64];
    __shared__ int flcnt;

    int br = blockIdx.x;
    int b = br >> 2, r = br & 3;
    int t = threadIdx.x;
    const int* hp = h_ws + (size_t)br * L_;

    if (t == 0) flcnt = 0;

    // load keys (coalesced int4), strip + remember flags
    int key[16]; unsigned fmask = 0;
    const int4* hp4 = (const int4*)(hp + t * 16);
    #pragma unroll
    for (int g = 0; g < 4; g++) {
        int4 v = hp4[g];
        int raw[4] = { v.x, v.y, v.z, v.w };
        #pragma unroll
        for (int j = 0; j < 4; j++) {
            int k = g * 4 + j;
            key[k] = raw[j] & 63;
            if (raw[j] & (1 << 30)) fmask |= 1u << k;
        }
    }
    __syncthreads();   // flcnt=0 visible

    if (fmask) {
        #pragma unroll
        for (int k = 0; k < 16; k++)
            if (fmask & (1u << k)) {
                int slot = atomicAdd(&flcnt, 1);
                sb_s[slot] = (unsigned short)(t * 16 + k);   // row l (<=4096 entries)
            }
    }
    __syncthreads();

    {   // wave-cooperative exact fp64 resolve (reference tie order)
        int wid = t >> 6, lane = t & 63;
        int fc = flcnt;
        for (int e = wid; e < fc; e += 4) {
            int l = sb_s[e];
            int n = lane & 31;
            const float* rpb = rm + (size_t)b * 8192 + r * 32 + n;
            const float* qr = q + ((size_t)(b * L_ + l)) * 64;
            double s2 = 0.0, dot = 0.0;
            for (int d = 0; d < 64; d++) {
                double m = (double)rpb[d * 128];
                s2 += m * m;
                dot += (double)qr[d] * m;
            }
            double acc = dot / sqrt(s2);
            double v = (lane < 32) ? acc : -acc;
            int idx = lane;
            #pragma unroll
            for (int off = 1; off < 64; off <<= 1) {
                double ov = __shfl_xor(v, off);
                int   oidx = __shfl_xor(idx, off);
                if (ov > v || (ov == v && oidx < idx)) { v = ov; idx = oidx; }
            }
            if (lane == 0) p_s[l] = (unsigned short)idx;
        }
    }
    __syncthreads();
    if (fmask) {
        #pragma unroll
        for (int k = 0; k < 16; k++)
            if (fmask & (1u << k)) key[k] = p_s[t * 16 + k];
    }

    // zero histogram (16448 u16 = 8224 u32)
    unsigned int* cz = (unsigned int*)cnt;
    #pragma unroll
    for (int i = 0; i < 33; i++) {
        int idx = i * 256 + t;
        if (idx < 8224) cz[idx] = 0;
    }
    __syncthreads();

    // per-thread histogram
    #pragma unroll
    for (int k = 0; k < 16; k++) {
        unsigned short* c = &cnt[key[k] * 257 + t];
        *c = (unsigned short)(*c + 1);
    }
    __syncthreads();

    // within-segment exclusive prefix
    int u = t & 63, s = t >> 6;
    {
        int run = 0;
        int base_idx = u * 257 + s * 64;
        #pragma unroll 16
        for (int i = 0; i < 64; i++) {
            int c = cnt[base_idx + i];
            cnt[base_idx + i] = (unsigned short)run;
            run += c;
        }
        part[s * 64 + u] = run;
    }
    __syncthreads();

    if (t < 64) {
        int p0 = part[t], p1 = part[64 + t], p2 = part[128 + t], p3 = part[192 + t];
        int tot = p0 + p1 + p2 + p3;
        int v = tot;
        #pragma unroll
        for (int off = 1; off < 64; off <<= 1) {
            int o = __shfl_up(v, off);
            if (t >= off) v += o;
        }
        int base = v - tot;              // first spos of bucket t
        bstart_s[t] = base;
        part[t]       = base;
        part[64 + t]  = base + p0;
        part[128 + t] = base + p0 + p1;
        part[192 + t] = base + p0 + p1 + p2;
    }
    __syncthreads();

    // scatter: pos = bucket/segment base + within-segment offset (stable)
    int sbase = s * 64;
    #pragma unroll
    for (int k = 0; k < 16; k++) {
        int uk = key[k];
        unsigned short* c = &cnt[uk * 257 + t];
        int pos = part[sbase + uk] + *c;
        *c = (unsigned short)(*c + 1);
        int idx = t * 16 + k;
        oi_s[(idx >> 4) * 17 + (idx & 15)] = (unsigned short)pos;
        p_s[pos]  = (unsigned short)idx;
        sb_s[pos] = (unsigned short)bstart_s[uk];
    }
    __syncthreads();

    // coalesced outputs: metaA (int2 per spos) + this round's bk byte per orig idx
    int2* mp = metaA + (size_t)br * L_;
    unsigned char* pb = packB + ((size_t)b * L_) * 4 + r;
    #pragma unroll
    for (int k = 0; k < 16; k++) {
        int e = k * 256 + t;
        mp[e] = make_int2((int)sb_s[e], (int)p_s[e]);
        int pos = (int)oi_s[(e >> 4) * 17 + (e & 15)];
        pb[(size_t)e * 4] = (unsigned char)(pos >> 6);
    }
}

// K3: MFMA fused attention (256 threads, strides 72/136). BOTH matmuls use
// swapped operands: QK^T as S^T = K*Q^T so each lane owns 32 scores of ONE
// q-row (q = w*16+l15) -> softmax row-reduce is in-register + 2 shfl_xor;
// PV as O^T = V^T*P^T so the epilogue is 4 x 8B f16x4 stores per thread.
// Ph pre-normalized (inv + count folded); f16x4 Ph writes (2-way, free).
__global__ __launch_bounds__(256, 4) void k_attn(const float* __restrict__ qscale_g,
                                                 const _Float16* __restrict__ khf,
                                                 const _Float16* __restrict__ vhf,
                                                 const int2* __restrict__ metaA,
                                                 const unsigned int* __restrict__ packA,
                                                 float* __restrict__ lse_ws,
                                                 _Float16* __restrict__ attn_ws) {
    __shared__ _Float16 Ksh[128 * 72];    // 18432 B; overlaid by Ph[64][136]
    __shared__ _Float16 Vt[64 * 136];     // 17408 B
    __shared__ int4 kmeta[128];

    int xcd = blockIdx.x & 7, slot = blockIdx.x >> 3;
    int b = xcd * 2 + (slot >> 8);
    int rem = slot & 255, n = rem >> 2, r = rem & 3;
    int tid = threadIdx.x;
    int w = tid >> 6, lane = tid & 63, quad = lane >> 4, l15 = lane & 15;
    int hibase = (b * 4 + r) * L_;
    const int2* mpA = metaA + hibase;
    int nprev = (n + 63) & 63;

    {   // stage K + publish kmeta
        int j = tid >> 1, dh = (tid & 1) * 32;
        int spos = (j < 64) ? (nprev * 64 + j) : (n * 64 + (j - 64));
        int2 ma = mpA[spos];
        const _Float16* src = khf + ((size_t)(b * L_ + ma.y)) * 64 + dh;
        f16x8 t0 = *(const f16x8*)(src);
        f16x8 t1 = *(const f16x8*)(src + 8);
        f16x8 t2 = *(const f16x8*)(src + 16);
        f16x8 t3 = *(const f16x8*)(src + 24);
        if (dh == 0) {
            unsigned int pk = packA[b * L_ + ma.y];
            unsigned int pm1 = ((pk | 0x40404040u) - 0x01010101u) & 0x3f3f3f3fu;
            kmeta[j] = make_int4(ma.x, ma.y, (int)pk, (int)pm1);
        }
        *(f16x8*)&Ksh[j * 72 + dh + 0]  = t0;
        *(f16x8*)&Ksh[j * 72 + dh + 8]  = t1;
        *(f16x8*)&Ksh[j * 72 + dh + 16] = t2;
        *(f16x8*)&Ksh[j * 72 + dh + 24] = t3;
    }
    __syncthreads();   // b1: Ksh + kmeta ready

    {   // stage V^T: thread = (row-pair m, d-quarter sub); rows from kmeta
        int m = tid >> 2, sub = tid & 3;
        int y0 = kmeta[2 * m].y, y1 = kmeta[2 * m + 1].y;
        const _Float16* v0 = vhf + ((size_t)(b * L_ + y0)) * 64 + sub * 16;
        const _Float16* v1 = vhf + ((size_t)(b * L_ + y1)) * 64 + sub * 16;
        f16x8 a00 = *(const f16x8*)v0, a01 = *(const f16x8*)(v0 + 8);
        f16x8 a10 = *(const f16x8*)v1, a11 = *(const f16x8*)(v1 + 8);
        #pragma unroll
        for (int d = 0; d < 8; d++) {
            f16x2 hv = { a00[d], a10[d] };
            *(f16x2*)&Vt[(sub * 16 + d) * 136 + 2 * m] = hv;
            f16x2 hw = { a01[d], a11[d] };
            *(f16x2*)&Vt[(sub * 16 + 8 + d) * 136 + 2 * m] = hw;
        }
    }

    // A-frags from LDS: q rows ARE Ksh rows 64..127 (khf, same scaling)
    f16x8 afr[2];
    afr[0] = *(const f16x8*)&Ksh[(64 + w * 16 + l15) * 72 + quad * 8];
    afr[1] = *(const f16x8*)&Ksh[(64 + w * 16 + l15) * 72 + 32 + quad * 8];

    // per-lane q meta (q = w*16 + l15) — hidden under the QK MFMA cluster
    int4 qm = kmeta[64 + w * 16 + l15];
    float qs = qscale_g[(size_t)b * L_ + qm.y];

    // QK^T SWAPPED: acc[jt][reg] = S[k = jt*16+quad*4+reg][q = w*16+l15]
    f32x4 acc[8];
    #pragma unroll
    for (int jt = 0; jt < 8; jt++) acc[jt] = (f32x4){0.f, 0.f, 0.f, 0.f};
    __builtin_amdgcn_s_setprio(1);
    #pragma unroll
    for (int jt = 0; jt < 8; jt++) {
        #pragma unroll
        for (int kt = 0; kt < 2; kt++) {
            f16x8 bfr = *(const f16x8*)&Ksh[(jt * 16 + l15) * 72 + kt * 32 + quad * 8];
            acc[jt] = __builtin_amdgcn_mfma_f32_16x16x32_f16(bfr, afr[kt], acc[jt], 0, 0, 0);
        }
    }
    __builtin_amdgcn_s_setprio(0);
    __syncthreads();   // b2: all QK reads of Ksh done -> overlay Ph

    _Float16* Ph = Ksh;
    // lane-local masked scores: valid k-range [lo, si); self at si.
    int lo = qm.x - (n - 1) * 64;
    int width = w * 16 + l15 + 64 - lo;       // si - lo
    int jq = quad * 4 - lo;
    #pragma unroll
    for (int jt = 0; jt < 8; jt++) {
        #pragma unroll
        for (int reg = 0; reg < 4; reg++) {
            float v = acc[jt][reg] * qs;
            int ju = jt * 16 + jq + reg;
            v = ((unsigned)ju < (unsigned)width) ? v : -1.4426951e9f;
            if (ju == width) v = -144269.50f; // self: -1e5 * log2e
            acc[jt][reg] = v;
        }
    }
    // in-register max tree + 2-shfl cross-quad combine
    float mx[8];
    #pragma unroll
    for (int jt = 0; jt < 8; jt++)
        mx[jt] = fmaxf(fmaxf(acc[jt][0], acc[jt][1]), fmaxf(acc[jt][2], acc[jt][3]));
    float m = fmaxf(fmaxf(fmaxf(mx[0], mx[1]), fmaxf(mx[2], mx[3])),
                    fmaxf(fmaxf(mx[4], mx[5]), fmaxf(mx[6], mx[7])));
    m = fmaxf(m, __shfl_xor(m, 16));
    m = fmaxf(m, __shfl_xor(m, 32));
    // exp2 in place + sum tree
    float ps[8];
    #pragma unroll
    for (int jt = 0; jt < 8; jt++) {
        float t0 = __builtin_amdgcn_exp2f(acc[jt][0] - m);
        float t1 = __builtin_amdgcn_exp2f(acc[jt][1] - m);
        float t2 = __builtin_amdgcn_exp2f(acc[jt][2] - m);
        float t3 = __builtin_amdgcn_exp2f(acc[jt][3] - m);
        acc[jt][0] = t0; acc[jt][1] = t1; acc[jt][2] = t2; acc[jt][3] = t3;
        ps[jt] = (t0 + t1) + (t2 + t3);
    }
    float sum = ((ps[0] + ps[1]) + (ps[2] + ps[3])) + ((ps[4] + ps[5]) + (ps[6] + ps[7]));
    sum += __shfl_xor(sum, 16);
    sum += __shfl_xor(sum, 32);
    float inv = __builtin_amdgcn_rcpf(sum);
    if (quad == 0)
        lse_ws[hibase + qm.y] = m * 0.6931472f + __logf(sum);
    // count-divide + vectorized Ph write (f16x4 per jt)
    {
        int kbase = quad * 4;
        #pragma unroll
        for (int jt = 0; jt < 8; jt++) {
            f16x4 pv;
            #pragma unroll
            for (int reg = 0; reg < 4; reg++) {
                int kz = kmeta[jt * 16 + kbase + reg].z;
                int z1 = kz ^ qm.z;
                int z2 = kz ^ qm.w;
                int nz = __popc((z1 + 0x7f7f7f7f) & 0x80808080)
                       + __popc((z2 + 0x7f7f7f7f) & 0x80808080);
                pv[reg] = (_Float16)(acc[jt][reg] * inv * __builtin_amdgcn_rcpf((float)(8 - nz)));
            }
            *(f16x4*)&Ph[(w * 16 + l15) * 136 + jt * 16 + kbase] = pv;
        }
    }
    __syncthreads();   // b3: Ph ready

    // PV as O^T = V^T * P^T (swapped operands): lane -> O[q=w*16+l15][d contig]
    f32x4 oacc[4];
    #pragma unroll
    for (int nt = 0; nt < 4; nt++) oacc[nt] = (f32x4){0.f, 0.f, 0.f, 0.f};
    __builtin_amdgcn_s_setprio(1);
    #pragma unroll
    for (int kt = 0; kt < 4; kt++) {
        f16x8 pa = *(const f16x8*)&Ph[(w * 16 + l15) * 136 + kt * 32 + quad * 8];
        #pragma unroll
        for (int nt = 0; nt < 4; nt++) {
            f16x8 vb = *(const f16x8*)&Vt[(nt * 16 + l15) * 136 + kt * 32 + quad * 8];
            oacc[nt] = __builtin_amdgcn_mfma_f32_16x16x32_f16(vb, pa, oacc[nt], 0, 0, 0);
        }
    }
    __builtin_amdgcn_s_setprio(0);

    // direct store epilogue: one row base per thread, 4 x 8B f16x4 stores.
    // O[q = w*16+l15][d = nt*16 + quad*4 + reg]
    {
        _Float16* dst = attn_ws + ((size_t)hibase + qm.y) * 64 + quad * 4;
        #pragma unroll
        for (int nt = 0; nt < 4; nt++) {
            f16x4 v;
            v[0] = (_Float16)oacc[nt][0];
            v[1] = (_Float16)oacc[nt][1];
            v[2] = (_Float16)oacc[nt][2];
            v[3] = (_Float16)oacc[nt][3];
            *(f16x4*)(dst + nt * 16) = v;
        }
    }
}

// K4a: per (b,r) softmax-over-L stats of lse
__global__ __launch_bounds__(256) void k_rw(const float* __restrict__ lse_ws,
                                            float* __restrict__ rwmax,
                                            float* __restrict__ rwsum) {
    __shared__ float  red[256];
    __shared__ double redd[256];
    int br = blockIdx.x;
    const float* lp = lse_ws + (size_t)br * L_;
    int t = threadIdx.x;
    float m = -1e30f;
    for (int k = t; k < L_; k += 256) m = fmaxf(m, lp[k]);
    red[t] = m; __syncthreads();
    for (int s2 = 128; s2 > 0; s2 >>= 1) {
        if (t < s2) red[t] = fmaxf(red[t], red[t + s2]);
        __syncthreads();
    }
    float mm = red[0];
    double s = 0.0;
    for (int k = t; k < L_; k += 256) s += (double)expf(lp[k] - mm);
    redd[t] = s; __syncthreads();
    for (int s2 = 128; s2 > 0; s2 >>= 1) {
        if (t < s2) redd[t] += redd[t + s2];
        __syncthreads();
    }
    if (t == 0) { rwmax[br] = mm; rwsum[br] = (float)redd[0]; }
}

// K4b: vectorized combine — thread = (b,l, d-octet)
__global__ __launch_bounds__(256) void k_out(const _Float16* __restrict__ attn_ws,
                                             const float* __restrict__ lse_ws,
                                             const float* __restrict__ rwmax,
                                             const float* __restrict__ rwsum,
                                             float* __restrict__ out) {
    int gid = blockIdx.x * 256 + threadIdx.x;   // B*L*8
    int g = gid & 7;
    size_t row = (size_t)(gid >> 3);            // b*L + l
    int b = (int)(row >> 12), l = (int)(row & 4095);
    float o[8];
    #pragma unroll
    for (int k = 0; k < 8; k++) o[k] = 0.f;
    #pragma unroll
    for (int r = 0; r < 4; r++) {
        int br = b * 4 + r;
        float wgt = __expf(lse_ws[(size_t)br * L_ + l] - rwmax[br])
                  * __builtin_amdgcn_rcpf(rwsum[br]);
        f16x8 av = *(const f16x8*)&attn_ws[(((size_t)br * L_ + l) << 6) + g * 8];
        #pragma unroll
        for (int k = 0; k < 8; k++) o[k] += (float)av[k] * wgt;
    }
    float4* op = (float4*)(out + row * 64 + g * 8);
    op[0] = make_float4(o[0], o[1], o[2], o[3]);
    op[1] = make_float4(o[4], o[5], o[6], o[7]);
}

extern "C" void kernel_launch(void* const* d_in, const int* in_sizes, int n_in,
                              void* d_out, int out_size, void* d_ws, size_t ws_size,
                              hipStream_t stream) {
    const float* query = (const float*)d_in[0];
    const float* value = (const float*)d_in[1];
    const float* rm    = (const float*)d_in[2];
    char* ws = (char*)d_ws;
    int*       h_ws   = (int*)(ws + ((size_t)1 << 20));
    float*     lse_ws = (float*)(ws + ((size_t)4 << 20));
    float*     rwmax  = (float*)(ws + ((size_t)5 << 20));
    float*     rwsum  = (float*)(ws + ((size_t)5 << 20) + 256);
    _Float16*  attn_ws= (_Float16*)(ws + ((size_t)6 << 20));
    int2*      metaA  = (int2*)(ws + ((size_t)41 << 20));
    unsigned char* packB = (unsigned char*)(ws + ((size_t)43 << 20));
    float*     qscale = (float*)(ws + ((size_t)45 << 20));
    _Float16*  khf    = (_Float16*)(ws + ((size_t)53 << 20));
    _Float16*  vhf    = (_Float16*)(ws + ((size_t)61 << 20));
    float*     out    = (float*)d_out;

    hipLaunchKernelGGL(k_hash,   dim3(1024), dim3(256), 0, stream, query, value, rm,
                       h_ws, qscale, khf, vhf);
    hipLaunchKernelGGL(k_sort,   dim3(64),   dim3(256), 0, stream, h_ws, query, rm,
                       metaA, packB);
    hipLaunchKernelGGL(k_attn,   dim3(4096), dim3(256), 0, stream,
                       qscale, khf, vhf, metaA, (const unsigned int*)packB, lse_ws, attn_ws);
    hipLaunchKernelGGL(k_rw,     dim3(64),   dim3(256), 0, stream, lse_ws, rwmax, rwsum);
    hipLaunchKernelGGL(k_out,    dim3(2048), dim3(256), 0, stream,
                       attn_ws, lse_ws, rwmax, rwsum, out);
}